// Round 9
// baseline (151.462 us; speedup 1.0000x reference)
//
#include <hip/hip_runtime.h>
#include <math.h>

#define Bb 2
#define Tt 256
#define Ee 512
#define Hh 8
#define Dd 64
#define E3 1536
#define SCP 260   // padded sc row stride

typedef float vfloat4 __attribute__((ext_vector_type(4)));

__device__ inline float4 ntload4(const float* p) {
    vfloat4 v = __builtin_nontemporal_load((const vfloat4*)p);
    return make_float4(v.x, v.y, v.z, v.w);
}

// cross-lane adds: xor1/xor2 via DPP quad_perm (VALU pipe), xor4 via ds_swizzle
template<int CTRL>
__device__ inline float dpp_addf(float v) {
    int x = __builtin_amdgcn_update_dpp(0, __float_as_int(v), CTRL, 0xF, 0xF, true);
    return v + __int_as_float(x);
}
__device__ inline float swz4_addf(float v) {
    int x = __builtin_amdgcn_ds_swizzle(__float_as_int(v), 0x101F); // lane ^= 4
    return v + __int_as_float(x);
}

// GEMM with wave-uniform A (VMEM same-address broadcast; no LDS for A) and
// B staged in double-buffered LDS (one b64/b32 read per k). VALU-bound by
// design: DS per 2-k = 12-16cy x 4 waves < 64cy VALU.
// Tile: (NW*8) rows x NT cols, 256 threads, 8 rows x NC cols per thread.
template<int NT, int NW>
__global__ __launch_bounds__(256) void gemm_sa2(
    const float* __restrict__ A, const float* __restrict__ W,
    const float* __restrict__ bias, float* __restrict__ C,
    int M, int N, int K)
{
    constexpr int NC = NT / 64;        // cols per lane (1|2)
    constexpr int NI = NT / 32;        // float4 staging chunks per thread
    __shared__ float Bs[2][32][NT];
    const int tid  = threadIdx.x;
    const int lane = tid & 63;
    const int wv   = tid >> 6;
    const int n0   = blockIdx.x * NT;
    const int m0   = blockIdx.y * (NW * 8);

    // staging map: row kr, i-th chunk at col c8*4 + i*32 (bank starts 4*c8:
    // conflict-free; global side 8 lanes cover 128B contiguous)
    const int kr = tid >> 3;           // 0..31
    const int c8 = tid & 7;
    const float* wp = W + (size_t)kr * N + n0 + c8 * 4;

    const float* ap = A + (size_t)(m0 + wv * 8) * K;   // wave-uniform

    float acc[8][NC];
    #pragma unroll
    for (int r = 0; r < 8; ++r)
        #pragma unroll
        for (int c = 0; c < NC; ++c) acc[r][c] = 0.f;

    // prologue: stage B tile 0
    #pragma unroll
    for (int i = 0; i < NI; ++i)
        *(float4*)&Bs[0][kr][c8 * 4 + i * 32] = *(const float4*)(wp + i * 32);

    // prologue: A regs for k4-group 0 (ping-pong, statically indexed)
    float4 ab[2][8];
    #pragma unroll
    for (int r = 0; r < 8; ++r)
        ab[0][r] = *(const float4*)(ap + (size_t)r * K);

    const int nsteps = K >> 5;
    for (int s = 0; s < nsteps; ++s) {
        __syncthreads();
        const int cur = s & 1;
        float4 nb[NI];
        const bool pf = (s + 1 < nsteps);
        if (pf) {
            const float* wn = wp + (size_t)(s + 1) * 32 * N;
            #pragma unroll
            for (int i = 0; i < NI; ++i) nb[i] = *(const float4*)(wn + i * 32);
        }
        #pragma unroll
        for (int k4 = 0; k4 < 8; ++k4) {
            const int cb = k4 & 1, nbuf = cb ^ 1;
            const int gn = s * 8 + k4 + 1;            // next A k4-group
            if (k4 < 7 || pf) {
                const float* an = ap + (size_t)gn * 4;
                #pragma unroll
                for (int r = 0; r < 8; ++r)
                    ab[nbuf][r] = *(const float4*)(an + (size_t)r * K);
            }
            #pragma unroll
            for (int kk = 0; kk < 4; ++kk) {
                const int k = k4 * 4 + kk;
                float bv[NC];
                if (NC == 2) {
                    const float2 b2 = *(const float2*)&Bs[cur][k][lane * 2];
                    bv[0] = b2.x; bv[1] = b2.y;
                } else {
                    bv[0] = Bs[cur][k][lane];
                }
                #pragma unroll
                for (int r = 0; r < 8; ++r) {
                    const float a = (kk == 0) ? ab[cb][r].x : (kk == 1) ? ab[cb][r].y
                                   : (kk == 2) ? ab[cb][r].z : ab[cb][r].w;
                    #pragma unroll
                    for (int c = 0; c < NC; ++c)
                        acc[r][c] = fmaf(a, bv[c], acc[r][c]);
                }
            }
        }
        if (pf) {
            #pragma unroll
            for (int i = 0; i < NI; ++i)
                *(float4*)&Bs[cur ^ 1][kr][c8 * 4 + i * 32] = nb[i];
        }
    }

    #pragma unroll
    for (int r = 0; r < 8; ++r) {
        const size_t row = (size_t)(m0 + wv * 8 + r);
        if (NC == 2) {
            float2 o;
            o.x = acc[r][0] + bias[n0 + lane * 2];
            o.y = acc[r][1] + bias[n0 + lane * 2 + 1];
            *(float2*)&C[row * N + n0 + lane * 2] = o;
        } else {
            C[row * N + n0 + lane] = acc[r][0] + bias[n0 + lane];
        }
    }
}

// Block = (b, t-pair). 512 threads / 8 waves. q in VGPRs; mask/k/v prefetched
// ping-pong; score reduce via DPP+1 swizzle (DS ops /3).
__global__ __launch_bounds__(512, 2) void attn_kernel(
    const float* __restrict__ qkv,     // (B*T, 1536): [q|k|v]
    const float* __restrict__ mask,    // (B, T, T, 64)
    const float* __restrict__ pad,     // (B, T)
    float* __restrict__ o_attn,        // (B*T, 512)
    float* __restrict__ attn_w)        // (B*T, 256)
{
    __shared__ float sc[2][Hh][SCP];
    __shared__ float part[4][2][Hh][68];
    __shared__ float rrs[16];
    const int tid  = threadIdx.x;
    const int lane = tid & 63;
    const int wv   = tid >> 6;
    const int si   = lane >> 3;
    const int dq   = lane & 7;
    const int b    = blockIdx.x >> 7;
    const int t0   = (blockIdx.x & 127) * 2;

    // q fully into registers
    float4 qr[2][Hh][2];
    {
        const float* qb = qkv + (size_t)(b * Tt + t0) * E3 + dq * 8;
        #pragma unroll
        for (int t = 0; t < 2; ++t)
            #pragma unroll
            for (int h = 0; h < Hh; ++h) {
                qr[t][h][0] = *(const float4*)(qb + (size_t)t * E3 + h * 64);
                qr[t][h][1] = *(const float4*)(qb + (size_t)t * E3 + h * 64 + 4);
            }
    }

    const float scale = 0.125f;

    // ---- scores: mask ping-pong across c, k ping-pong across h ----
    const float* mbase0 = mask + (size_t)(b * Tt + t0) * Tt * Dd + dq * 8;
    const float* mbase1 = mbase0 + (size_t)Tt * Dd;
    float4 mc[2][4];
    {
        const int s0 = wv * 32 + si;
        const float* m0p = mbase0 + (size_t)s0 * Dd;
        const float* m1p = mbase1 + (size_t)s0 * Dd;
        mc[0][0] = ntload4(m0p); mc[0][1] = ntload4(m0p + 4);
        mc[0][2] = ntload4(m1p); mc[0][3] = ntload4(m1p + 4);
    }
    #pragma unroll
    for (int c = 0; c < 4; ++c) {
        const int s = wv * 32 + c * 8 + si;
        const int cb = c & 1, nbm = cb ^ 1;
        if (c < 3) {
            const int sn = s + 8;
            const float* m0p = mbase0 + (size_t)sn * Dd;
            const float* m1p = mbase1 + (size_t)sn * Dd;
            mc[nbm][0] = ntload4(m0p); mc[nbm][1] = ntload4(m0p + 4);
            mc[nbm][2] = ntload4(m1p); mc[nbm][3] = ntload4(m1p + 4);
        }
        const float4 ma0 = mc[cb][0], mb0 = mc[cb][1];
        const float4 ma1 = mc[cb][2], mb1 = mc[cb][3];
        const float* krow = qkv + (size_t)(b * Tt + s) * E3 + Ee + dq * 8;
        const float padv = pad[b * Tt + s];

        float4 kc[2][2];
        kc[0][0] = *(const float4*)(krow);
        kc[0][1] = *(const float4*)(krow + 4);
        #pragma unroll
        for (int h = 0; h < Hh; ++h) {
            const int hb = h & 1, hn = hb ^ 1;
            if (h < 7) {
                kc[hn][0] = *(const float4*)(krow + (h + 1) * 64);
                kc[hn][1] = *(const float4*)(krow + (h + 1) * 64 + 4);
            }
            const float4 ka = kc[hb][0], kb = kc[hb][1];
            const float4 qa0 = qr[0][h][0], qb0 = qr[0][h][1];
            const float4 qa1 = qr[1][h][0], qb1 = qr[1][h][1];
            float u0 = qa0.x * ka.x + qa0.y * ka.y;
            float w0 = qa0.y * ka.x - qa0.x * ka.y;
            float u1 = qa0.z * ka.z + qa0.w * ka.w;
            float w1 = qa0.w * ka.z - qa0.z * ka.w;
            float u2 = qb0.x * kb.x + qb0.y * kb.y;
            float w2 = qb0.y * kb.x - qb0.x * kb.y;
            float u3 = qb0.z * kb.z + qb0.w * kb.w;
            float w3 = qb0.w * kb.z - qb0.z * kb.w;
            float v0 = u0 * ma0.x + w0 * ma0.y + u1 * ma0.z + w1 * ma0.w
                     + u2 * mb0.x + w2 * mb0.y + u3 * mb0.z + w3 * mb0.w;
            float s0 = qa1.x * ka.x + qa1.y * ka.y;
            float r0 = qa1.y * ka.x - qa1.x * ka.y;
            float s1 = qa1.z * ka.z + qa1.w * ka.w;
            float r1 = qa1.w * ka.z - qa1.z * ka.w;
            float s2 = qb1.x * kb.x + qb1.y * kb.y;
            float r2 = qb1.y * kb.x - qb1.x * kb.y;
            float s3 = qb1.z * kb.z + qb1.w * kb.w;
            float r3 = qb1.w * kb.z - qb1.z * kb.w;
            float v1 = s0 * ma1.x + r0 * ma1.y + s1 * ma1.z + r1 * ma1.w
                     + s2 * mb1.x + r2 * mb1.y + s3 * mb1.z + r3 * mb1.w;
            // reduce over dq: xor1+xor2 (DPP/VALU) + xor4 (1 swizzle)
            v0 = dpp_addf<0xB1>(v0); v0 = dpp_addf<0x4E>(v0); v0 = swz4_addf(v0);
            v1 = dpp_addf<0xB1>(v1); v1 = dpp_addf<0x4E>(v1); v1 = swz4_addf(v1);
            if (dq == 0) {
                sc[0][h][s] = v0 * scale + padv;
                sc[1][h][s] = v1 * scale + padv;
            }
        }
    }
    __syncthreads();

    // ---- softmax: 16 rows (t,h) ----
    #pragma unroll
    for (int r = 0; r < 2; ++r) {
        const int row = wv * 2 + r;
        float* pr = &sc[0][0][0] + row * SCP;
        float4 xv = *(const float4*)&pr[lane * 4];
        float mx = fmaxf(fmaxf(xv.x, xv.y), fmaxf(xv.z, xv.w));
        #pragma unroll
        for (int dlt = 32; dlt >= 1; dlt >>= 1) mx = fmaxf(mx, __shfl_xor(mx, dlt));
        float4 ev;
        ev.x = __expf(xv.x - mx);
        ev.y = __expf(xv.y - mx);
        ev.z = __expf(xv.z - mx);
        ev.w = __expf(xv.w - mx);
        float sum = (ev.x + ev.y) + (ev.z + ev.w);
        #pragma unroll
        for (int dlt = 32; dlt >= 1; dlt >>= 1) sum += __shfl_xor(sum, dlt);
        *(float4*)&pr[lane * 4] = ev;
        if (lane == 0) rrs[row] = 1.0f / sum;
    }
    __syncthreads();

    // ---- attn_weights ----
    {
        const int tt = tid >> 8, s2 = tid & 255;
        float aw = 0.f;
        #pragma unroll
        for (int h = 0; h < Hh; ++h) aw += sc[tt][h][s2] * rrs[tt * 8 + h];
        attn_w[(size_t)(b * Tt + t0 + tt) * Tt + s2] = aw * 0.125f;
    }

    // ---- PV: thread (sh, h, d4); v rows prefetched ping-pong ----
    {
        const int sh = tid >> 7;
        const int h  = (tid >> 4) & 7;
        const int d4 = tid & 15;
        const float* vb = qkv + (size_t)b * Tt * E3 + 2 * Ee + h * 64 + d4 * 4;
        float4 o0 = make_float4(0.f, 0.f, 0.f, 0.f);
        float4 o1 = make_float4(0.f, 0.f, 0.f, 0.f);
        const int sBeg = sh * 64;
        float4 vc[2][4];
        #pragma unroll
        for (int i = 0; i < 4; ++i)
            vc[0][i] = *(const float4*)(vb + (size_t)(sBeg + i) * E3);
        #pragma unroll
        for (int it = 0; it < 16; ++it) {
            const int s2 = sBeg + it * 4;
            const int cb = it & 1, nbv = cb ^ 1;
            if (it < 15) {
                #pragma unroll
                for (int i = 0; i < 4; ++i)
                    vc[nbv][i] = *(const float4*)(vb + (size_t)(s2 + 4 + i) * E3);
            }
            const float4 p0 = *(const float4*)&sc[0][h][s2];
            const float4 p1 = *(const float4*)&sc[1][h][s2];
            const float4 va = vc[cb][0], vbv = vc[cb][1], vcv = vc[cb][2], vd = vc[cb][3];
            o0.x = fmaf(p0.x, va.x, o0.x);  o0.y = fmaf(p0.x, va.y, o0.y);
            o0.z = fmaf(p0.x, va.z, o0.z);  o0.w = fmaf(p0.x, va.w, o0.w);
            o0.x = fmaf(p0.y, vbv.x, o0.x); o0.y = fmaf(p0.y, vbv.y, o0.y);
            o0.z = fmaf(p0.y, vbv.z, o0.z); o0.w = fmaf(p0.y, vbv.w, o0.w);
            o0.x = fmaf(p0.z, vcv.x, o0.x); o0.y = fmaf(p0.z, vcv.y, o0.y);
            o0.z = fmaf(p0.z, vcv.z, o0.z); o0.w = fmaf(p0.z, vcv.w, o0.w);
            o0.x = fmaf(p0.w, vd.x, o0.x);  o0.y = fmaf(p0.w, vd.y, o0.y);
            o0.z = fmaf(p0.w, vd.z, o0.z);  o0.w = fmaf(p0.w, vd.w, o0.w);
            o1.x = fmaf(p1.x, va.x, o1.x);  o1.y = fmaf(p1.x, va.y, o1.y);
            o1.z = fmaf(p1.x, va.z, o1.z);  o1.w = fmaf(p1.x, va.w, o1.w);
            o1.x = fmaf(p1.y, vbv.x, o1.x); o1.y = fmaf(p1.y, vbv.y, o1.y);
            o1.z = fmaf(p1.y, vbv.z, o1.z); o1.w = fmaf(p1.y, vbv.w, o1.w);
            o1.x = fmaf(p1.z, vcv.x, o1.x); o1.y = fmaf(p1.z, vcv.y, o1.y);
            o1.z = fmaf(p1.z, vcv.z, o1.z); o1.w = fmaf(p1.z, vcv.w, o1.w);
            o1.x = fmaf(p1.w, vd.x, o1.x);  o1.y = fmaf(p1.w, vd.y, o1.y);
            o1.z = fmaf(p1.w, vd.z, o1.z);  o1.w = fmaf(p1.w, vd.w, o1.w);
        }
        *(float4*)&part[sh][0][h][d4 * 4] = o0;
        *(float4*)&part[sh][1][h][d4 * 4] = o1;
    }
    __syncthreads();

    // ---- reduce s-quarters + normalize + write ----
    {
        const int t  = tid >> 8;
        const int n2 = tid & 255;
        const int h  = n2 >> 5;
        const int dc = (2 * n2) & 63;
        const float rr = rrs[t * 8 + h];
        float ax = 0.f, ay = 0.f;
        #pragma unroll
        for (int s = 0; s < 4; ++s) {
            const float2 p = *(const float2*)&part[s][t][h][dc];
            ax += p.x; ay += p.y;
        }
        float2 o;
        o.x = ax * rr; o.y = ay * rr;
        *(float2*)&o_attn[(size_t)(b * Tt + t0 + t) * Ee + 2 * n2] = o;
    }
}

extern "C" void kernel_launch(void* const* d_in, const int* in_sizes, int n_in,
                              void* d_out, int out_size, void* d_ws, size_t ws_size,
                              hipStream_t stream) {
    const float* x    = (const float*)d_in[0];
    const float* mask = (const float*)d_in[1];
    const float* pad  = (const float*)d_in[2];
    const float* Wqkv = (const float*)d_in[3];
    const float* bqkv = (const float*)d_in[4];
    const float* Wo   = (const float*)d_in[5];
    const float* bo   = (const float*)d_in[6];

    float* out    = (float*)d_out;               // o (B*T*E) then attn_w (B*T*T)
    float* qkv    = (float*)d_ws;                // B*T*3E floats
    float* o_attn = qkv + (size_t)Bb * Tt * E3;  // B*T*E floats

    // qkv = x @ Wqkv + bqkv   (32x128 tiles: grid 12 x 16 = 192 blocks)
    gemm_sa2<128, 4><<<dim3(E3 / 128, (Bb * Tt) / 32), 256, 0, stream>>>(
        x, Wqkv, bqkv, qkv, Bb * Tt, E3, Ee);

    // fused rotary scores + softmax + attn_weights + PV
    attn_kernel<<<dim3(Bb * (Tt / 2)), 512, 0, stream>>>(
        qkv, mask, pad, o_attn, out + (size_t)Bb * Tt * Ee);

    // out = o_attn @ Wo + bo  (32x64 tiles: grid 8 x 16 = 128 blocks)
    gemm_sa2<64, 4><<<dim3(Ee / 64, (Bb * Tt) / 32), 256, 0, stream>>>(
        o_attn, Wo, bo, out, Bb * Tt, Ee, Ee);
}

// Round 10
// 64.840 us; speedup vs baseline: 2.3359x; 2.3359x over previous
//
#include <hip/hip_runtime.h>
#include <math.h>

#define Bb 2
#define Tt 256
#define Ee 512
#define Hh 8
#define Dd 64
#define E3 1536
#define SCP 260   // padded sc row stride

typedef float vfloat4 __attribute__((ext_vector_type(4)));

__device__ inline float4 ntload4(const float* p) {
    vfloat4 v = __builtin_nontemporal_load((const vfloat4*)p);
    return make_float4(v.x, v.y, v.z, v.w);
}

// cross-lane adds: xor1/xor2 via DPP quad_perm (VALU pipe), xor4 via ds_swizzle
template<int CTRL>
__device__ inline float dpp_addf(float v) {
    int x = __builtin_amdgcn_update_dpp(0, __float_as_int(v), CTRL, 0xF, 0xF, true);
    return v + __int_as_float(x);
}
__device__ inline float swz4_addf(float v) {
    int x = __builtin_amdgcn_ds_swizzle(__float_as_int(v), 0x101F); // lane ^= 4
    return v + __int_as_float(x);
}

// Double-buffered LDS GEMM (proven r5/r8): C = A@W + bias.
// Tile (RPT*16)x64, BK=32, 256 threads, RPT x 4 outputs/thread.
// DS-pipe model: per 2-k per wave DS = RPT*6 + 24 cy (shared per CU),
// VALU = 16*RPT cy (parallel on 4 SIMDs) -> ~3x DS-bound; structural floor.
template<int RPT>
__global__ __launch_bounds__(256) void gemm_db(
    const float* __restrict__ A, const float* __restrict__ W,
    const float* __restrict__ bias, float* __restrict__ C,
    int M, int N, int K)
{
    __shared__ float As[2][RPT * 16][36];
    __shared__ float Bs[2][32][68];
    const int tid = threadIdx.x;
    const int tx = tid & 15;
    const int ty = tid >> 4;
    const int n0 = blockIdx.x * 64;
    const int m0 = blockIdx.y * (RPT * 16);

    // A staging map per RPT: RPT*16 rows x 32 k-floats, 256 threads
    const int ar = (RPT == 4) ? (tid >> 2) : (RPT == 2) ? (tid >> 3) : (tid >> 4);
    const int ak = (RPT == 4) ? ((tid & 3) * 8)
                 : (RPT == 2) ? ((tid & 7) * 4) : ((tid & 15) * 2);
    const int bk = tid >> 4;
    const int bc = (tid & 15) * 4;

    const float* aP = A + (size_t)(m0 + ar) * K + ak;
    const float* wP = W + (size_t)bk * N + n0 + bc;
    const size_t wRow16 = (size_t)16 * N;

    if (RPT == 4) {
        *(float4*)&As[0][ar][ak]     = *(const float4*)aP;
        *(float4*)&As[0][ar][ak + 4] = *(const float4*)(aP + 4);
    } else if (RPT == 2) {
        *(float4*)&As[0][ar][ak] = *(const float4*)aP;
    } else {
        *(float2*)&As[0][ar][ak] = *(const float2*)aP;
    }
    *(float4*)&Bs[0][bk][bc]      = *(const float4*)wP;
    *(float4*)&Bs[0][bk + 16][bc] = *(const float4*)(wP + wRow16);

    float acc[RPT][4];
    #pragma unroll
    for (int r = 0; r < RPT; ++r)
        #pragma unroll
        for (int j = 0; j < 4; ++j) acc[r][j] = 0.f;

    const int nsteps = K >> 5;
    for (int s = 0; s < nsteps; ++s) {
        __syncthreads();
        const int cur = s & 1, nxt = cur ^ 1;

        float4 na0, na1; float2 na2; float4 nb0, nb1;
        const bool pf = (s + 1 < nsteps);
        if (pf) {
            const float* aN = aP + (s + 1) * 32;
            const float* wN = wP + (size_t)(s + 1) * 32 * N;
            if (RPT == 4) { na0 = *(const float4*)aN; na1 = *(const float4*)(aN + 4); }
            else if (RPT == 2) { na0 = *(const float4*)aN; }
            else { na2 = *(const float2*)aN; }
            nb0 = *(const float4*)wN;
            nb1 = *(const float4*)(wN + wRow16);
        }

        #pragma unroll
        for (int k = 0; k < 32; k += 2) {
            float2 arow[RPT];
            #pragma unroll
            for (int r = 0; r < RPT; ++r)
                arow[r] = *(const float2*)&As[cur][ty * RPT + r][k];
            const float4 bA = *(const float4*)&Bs[cur][k][tx * 4];
            const float4 bB = *(const float4*)&Bs[cur][k + 1][tx * 4];
            #pragma unroll
            for (int r = 0; r < RPT; ++r) {
                acc[r][0] = fmaf(arow[r].x, bA.x, acc[r][0]);
                acc[r][1] = fmaf(arow[r].x, bA.y, acc[r][1]);
                acc[r][2] = fmaf(arow[r].x, bA.z, acc[r][2]);
                acc[r][3] = fmaf(arow[r].x, bA.w, acc[r][3]);
                acc[r][0] = fmaf(arow[r].y, bB.x, acc[r][0]);
                acc[r][1] = fmaf(arow[r].y, bB.y, acc[r][1]);
                acc[r][2] = fmaf(arow[r].y, bB.z, acc[r][2]);
                acc[r][3] = fmaf(arow[r].y, bB.w, acc[r][3]);
            }
        }

        if (pf) {
            if (RPT == 4) {
                *(float4*)&As[nxt][ar][ak]     = na0;
                *(float4*)&As[nxt][ar][ak + 4] = na1;
            } else if (RPT == 2) {
                *(float4*)&As[nxt][ar][ak] = na0;
            } else {
                *(float2*)&As[nxt][ar][ak] = na2;
            }
            *(float4*)&Bs[nxt][bk][bc]      = nb0;
            *(float4*)&Bs[nxt][bk + 16][bc] = nb1;
        }
    }

    const float4 bs4 = *(const float4*)&bias[n0 + tx * 4];
    #pragma unroll
    for (int r = 0; r < RPT; ++r) {
        float4 o;
        o.x = acc[r][0] + bs4.x;
        o.y = acc[r][1] + bs4.y;
        o.z = acc[r][2] + bs4.z;
        o.w = acc[r][3] + bs4.w;
        *(float4*)&C[(size_t)(m0 + ty * RPT + r) * N + n0 + tx * 4] = o;
    }
}

// Block = (b, t-pair). 512 threads / 8 waves. q in VGPRs; mask/k/v prefetched
// ping-pong; score reduce via DPP+1 swizzle. (r9-proven ~10us)
__global__ __launch_bounds__(512, 2) void attn_kernel(
    const float* __restrict__ qkv,     // (B*T, 1536): [q|k|v]
    const float* __restrict__ mask,    // (B, T, T, 64)
    const float* __restrict__ pad,     // (B, T)
    float* __restrict__ o_attn,        // (B*T, 512)
    float* __restrict__ attn_w)        // (B*T, 256)
{
    __shared__ float sc[2][Hh][SCP];
    __shared__ float part[4][2][Hh][68];
    __shared__ float rrs[16];
    const int tid  = threadIdx.x;
    const int lane = tid & 63;
    const int wv   = tid >> 6;
    const int si   = lane >> 3;
    const int dq   = lane & 7;
    const int b    = blockIdx.x >> 7;
    const int t0   = (blockIdx.x & 127) * 2;

    // q fully into registers
    float4 qr[2][Hh][2];
    {
        const float* qb = qkv + (size_t)(b * Tt + t0) * E3 + dq * 8;
        #pragma unroll
        for (int t = 0; t < 2; ++t)
            #pragma unroll
            for (int h = 0; h < Hh; ++h) {
                qr[t][h][0] = *(const float4*)(qb + (size_t)t * E3 + h * 64);
                qr[t][h][1] = *(const float4*)(qb + (size_t)t * E3 + h * 64 + 4);
            }
    }

    const float scale = 0.125f;

    // ---- scores: mask ping-pong across c, k ping-pong across h ----
    const float* mbase0 = mask + (size_t)(b * Tt + t0) * Tt * Dd + dq * 8;
    const float* mbase1 = mbase0 + (size_t)Tt * Dd;
    float4 mc[2][4];
    {
        const int s0 = wv * 32 + si;
        const float* m0p = mbase0 + (size_t)s0 * Dd;
        const float* m1p = mbase1 + (size_t)s0 * Dd;
        mc[0][0] = ntload4(m0p); mc[0][1] = ntload4(m0p + 4);
        mc[0][2] = ntload4(m1p); mc[0][3] = ntload4(m1p + 4);
    }
    #pragma unroll
    for (int c = 0; c < 4; ++c) {
        const int s = wv * 32 + c * 8 + si;
        const int cb = c & 1, nbm = cb ^ 1;
        if (c < 3) {
            const int sn = s + 8;
            const float* m0p = mbase0 + (size_t)sn * Dd;
            const float* m1p = mbase1 + (size_t)sn * Dd;
            mc[nbm][0] = ntload4(m0p); mc[nbm][1] = ntload4(m0p + 4);
            mc[nbm][2] = ntload4(m1p); mc[nbm][3] = ntload4(m1p + 4);
        }
        const float4 ma0 = mc[cb][0], mb0 = mc[cb][1];
        const float4 ma1 = mc[cb][2], mb1 = mc[cb][3];
        const float* krow = qkv + (size_t)(b * Tt + s) * E3 + Ee + dq * 8;
        const float padv = pad[b * Tt + s];

        float4 kc[2][2];
        kc[0][0] = *(const float4*)(krow);
        kc[0][1] = *(const float4*)(krow + 4);
        #pragma unroll
        for (int h = 0; h < Hh; ++h) {
            const int hb = h & 1, hn = hb ^ 1;
            if (h < 7) {
                kc[hn][0] = *(const float4*)(krow + (h + 1) * 64);
                kc[hn][1] = *(const float4*)(krow + (h + 1) * 64 + 4);
            }
            const float4 ka = kc[hb][0], kb = kc[hb][1];
            const float4 qa0 = qr[0][h][0], qb0 = qr[0][h][1];
            const float4 qa1 = qr[1][h][0], qb1 = qr[1][h][1];
            float u0 = qa0.x * ka.x + qa0.y * ka.y;
            float w0 = qa0.y * ka.x - qa0.x * ka.y;
            float u1 = qa0.z * ka.z + qa0.w * ka.w;
            float w1 = qa0.w * ka.z - qa0.z * ka.w;
            float u2 = qb0.x * kb.x + qb0.y * kb.y;
            float w2 = qb0.y * kb.x - qb0.x * kb.y;
            float u3 = qb0.z * kb.z + qb0.w * kb.w;
            float w3 = qb0.w * kb.z - qb0.z * kb.w;
            float v0 = u0 * ma0.x + w0 * ma0.y + u1 * ma0.z + w1 * ma0.w
                     + u2 * mb0.x + w2 * mb0.y + u3 * mb0.z + w3 * mb0.w;
            float s0 = qa1.x * ka.x + qa1.y * ka.y;
            float r0 = qa1.y * ka.x - qa1.x * ka.y;
            float s1 = qa1.z * ka.z + qa1.w * ka.w;
            float r1 = qa1.w * ka.z - qa1.z * ka.w;
            float s2 = qb1.x * kb.x + qb1.y * kb.y;
            float r2 = qb1.y * kb.x - qb1.x * kb.y;
            float s3 = qb1.z * kb.z + qb1.w * kb.w;
            float r3 = qb1.w * kb.z - qb1.z * kb.w;
            float v1 = s0 * ma1.x + r0 * ma1.y + s1 * ma1.z + r1 * ma1.w
                     + s2 * mb1.x + r2 * mb1.y + s3 * mb1.z + r3 * mb1.w;
            v0 = dpp_addf<0xB1>(v0); v0 = dpp_addf<0x4E>(v0); v0 = swz4_addf(v0);
            v1 = dpp_addf<0xB1>(v1); v1 = dpp_addf<0x4E>(v1); v1 = swz4_addf(v1);
            if (dq == 0) {
                sc[0][h][s] = v0 * scale + padv;
                sc[1][h][s] = v1 * scale + padv;
            }
        }
    }
    __syncthreads();

    // ---- softmax: 16 rows (t,h) ----
    #pragma unroll
    for (int r = 0; r < 2; ++r) {
        const int row = wv * 2 + r;
        float* pr = &sc[0][0][0] + row * SCP;
        float4 xv = *(const float4*)&pr[lane * 4];
        float mx = fmaxf(fmaxf(xv.x, xv.y), fmaxf(xv.z, xv.w));
        #pragma unroll
        for (int dlt = 32; dlt >= 1; dlt >>= 1) mx = fmaxf(mx, __shfl_xor(mx, dlt));
        float4 ev;
        ev.x = __expf(xv.x - mx);
        ev.y = __expf(xv.y - mx);
        ev.z = __expf(xv.z - mx);
        ev.w = __expf(xv.w - mx);
        float sum = (ev.x + ev.y) + (ev.z + ev.w);
        #pragma unroll
        for (int dlt = 32; dlt >= 1; dlt >>= 1) sum += __shfl_xor(sum, dlt);
        *(float4*)&pr[lane * 4] = ev;
        if (lane == 0) rrs[row] = 1.0f / sum;
    }
    __syncthreads();

    // ---- attn_weights ----
    {
        const int tt = tid >> 8, s2 = tid & 255;
        float aw = 0.f;
        #pragma unroll
        for (int h = 0; h < Hh; ++h) aw += sc[tt][h][s2] * rrs[tt * 8 + h];
        attn_w[(size_t)(b * Tt + t0 + tt) * Tt + s2] = aw * 0.125f;
    }

    // ---- PV: thread (sh, h, d4); v rows prefetched ping-pong ----
    {
        const int sh = tid >> 7;
        const int h  = (tid >> 4) & 7;
        const int d4 = tid & 15;
        const float* vb = qkv + (size_t)b * Tt * E3 + 2 * Ee + h * 64 + d4 * 4;
        float4 o0 = make_float4(0.f, 0.f, 0.f, 0.f);
        float4 o1 = make_float4(0.f, 0.f, 0.f, 0.f);
        const int sBeg = sh * 64;
        float4 vc[2][4];
        #pragma unroll
        for (int i = 0; i < 4; ++i)
            vc[0][i] = *(const float4*)(vb + (size_t)(sBeg + i) * E3);
        #pragma unroll
        for (int it = 0; it < 16; ++it) {
            const int s2 = sBeg + it * 4;
            const int cb = it & 1, nbv = cb ^ 1;
            if (it < 15) {
                #pragma unroll
                for (int i = 0; i < 4; ++i)
                    vc[nbv][i] = *(const float4*)(vb + (size_t)(s2 + 4 + i) * E3);
            }
            const float4 p0 = *(const float4*)&sc[0][h][s2];
            const float4 p1 = *(const float4*)&sc[1][h][s2];
            const float4 va = vc[cb][0], vbv = vc[cb][1], vcv = vc[cb][2], vd = vc[cb][3];
            o0.x = fmaf(p0.x, va.x, o0.x);  o0.y = fmaf(p0.x, va.y, o0.y);
            o0.z = fmaf(p0.x, va.z, o0.z);  o0.w = fmaf(p0.x, va.w, o0.w);
            o0.x = fmaf(p0.y, vbv.x, o0.x); o0.y = fmaf(p0.y, vbv.y, o0.y);
            o0.z = fmaf(p0.y, vbv.z, o0.z); o0.w = fmaf(p0.y, vbv.w, o0.w);
            o0.x = fmaf(p0.z, vcv.x, o0.x); o0.y = fmaf(p0.z, vcv.y, o0.y);
            o0.z = fmaf(p0.z, vcv.z, o0.z); o0.w = fmaf(p0.z, vcv.w, o0.w);
            o0.x = fmaf(p0.w, vd.x, o0.x);  o0.y = fmaf(p0.w, vd.y, o0.y);
            o0.z = fmaf(p0.w, vd.z, o0.z);  o0.w = fmaf(p0.w, vd.w, o0.w);
            o1.x = fmaf(p1.x, va.x, o1.x);  o1.y = fmaf(p1.x, va.y, o1.y);
            o1.z = fmaf(p1.x, va.z, o1.z);  o1.w = fmaf(p1.x, va.w, o1.w);
            o1.x = fmaf(p1.y, vbv.x, o1.x); o1.y = fmaf(p1.y, vbv.y, o1.y);
            o1.z = fmaf(p1.y, vbv.z, o1.z); o1.w = fmaf(p1.y, vbv.w, o1.w);
            o1.x = fmaf(p1.z, vcv.x, o1.x); o1.y = fmaf(p1.z, vcv.y, o1.y);
            o1.z = fmaf(p1.z, vcv.z, o1.z); o1.w = fmaf(p1.z, vcv.w, o1.w);
            o1.x = fmaf(p1.w, vd.x, o1.x);  o1.y = fmaf(p1.w, vd.y, o1.y);
            o1.z = fmaf(p1.w, vd.z, o1.z);  o1.w = fmaf(p1.w, vd.w, o1.w);
        }
        *(float4*)&part[sh][0][h][d4 * 4] = o0;
        *(float4*)&part[sh][1][h][d4 * 4] = o1;
    }
    __syncthreads();

    // ---- reduce s-quarters + normalize + write ----
    {
        const int t  = tid >> 8;
        const int n2 = tid & 255;
        const int h  = n2 >> 5;
        const int dc = (2 * n2) & 63;
        const float rr = rrs[t * 8 + h];
        float ax = 0.f, ay = 0.f;
        #pragma unroll
        for (int s = 0; s < 4; ++s) {
            const float2 p = *(const float2*)&part[s][t][h][dc];
            ax += p.x; ay += p.y;
        }
        float2 o;
        o.x = ax * rr; o.y = ay * rr;
        *(float2*)&o_attn[(size_t)(b * Tt + t0 + t) * Ee + 2 * n2] = o;
    }
}

extern "C" void kernel_launch(void* const* d_in, const int* in_sizes, int n_in,
                              void* d_out, int out_size, void* d_ws, size_t ws_size,
                              hipStream_t stream) {
    const float* x    = (const float*)d_in[0];
    const float* mask = (const float*)d_in[1];
    const float* pad  = (const float*)d_in[2];
    const float* Wqkv = (const float*)d_in[3];
    const float* bqkv = (const float*)d_in[4];
    const float* Wo   = (const float*)d_in[5];
    const float* bo   = (const float*)d_in[6];

    float* out    = (float*)d_out;               // o (B*T*E) then attn_w (B*T*T)
    float* qkv    = (float*)d_ws;                // B*T*3E floats
    float* o_attn = qkv + (size_t)Bb * Tt * E3;  // B*T*E floats

    // qkv = x @ Wqkv + bqkv   (64x64 tiles: grid 24 x 8 = 192 blocks)
    gemm_db<4><<<dim3(E3 / 64, (Bb * Tt) / 64), 256, 0, stream>>>(
        x, Wqkv, bqkv, qkv, Bb * Tt, E3, Ee);

    // fused rotary scores + softmax + attn_weights + PV  (256 blocks x 512 thr)
    attn_kernel<<<dim3(Bb * (Tt / 2)), 512, 0, stream>>>(
        qkv, mask, pad, o_attn, out + (size_t)Bb * Tt * Ee);

    // out = o_attn @ Wo + bo  (16x64 tiles: grid 8 x 32 = 256 blocks)
    gemm_db<1><<<dim3(Ee / 64, (Bb * Tt) / 16), 256, 0, stream>>>(
        o_attn, Wo, bo, out, Bb * Tt, Ee, Ee);
}